// Round 18
// baseline (204.814 us; speedup 1.0000x reference)
//
#include <hip/hip_runtime.h>

#define B 8
#define F 257
#define C 8
#define T 800
#define TAPS 5
#define DELAY 3
#define K 40         // TAPS*C
#define NCOL 48      // K + C
#define T0 7         // DELAY + TAPS - 1
#define BF (B*F)     // 2056

typedef __bf16 bf16x8 __attribute__((ext_vector_type(8)));
typedef __bf16 bf16x4 __attribute__((ext_vector_type(4)));
typedef float f32x4 __attribute__((ext_vector_type(4)));

struct PF { float4 v[3]; };

// ---------------- kernel 1: sqrt inverse power weights (0 for t<T0) ----------------
__global__ __launch_bounds__(256) void power_kernel(const float* __restrict__ sr,
                                                    const float* __restrict__ si,
                                                    float* __restrict__ W) {
    int bf = blockIdx.x;
    const float* srp = sr + (size_t)bf * C * T;
    const float* sip = si + (size_t)bf * C * T;
    int t0 = threadIdx.x * 4;
    if (t0 < T) {
        float s[4] = {0.f, 0.f, 0.f, 0.f};
#pragma unroll
        for (int c = 0; c < C; ++c) {
            float4 a = *(const float4*)(srp + c * T + t0);
            float4 b = *(const float4*)(sip + c * T + t0);
            s[0] = fmaf(a.x, a.x, fmaf(b.x, b.x, s[0]));
            s[1] = fmaf(a.y, a.y, fmaf(b.y, b.y, s[1]));
            s[2] = fmaf(a.z, a.z, fmaf(b.z, b.z, s[2]));
            s[3] = fmaf(a.w, a.w, fmaf(b.w, b.w, s[3]));
        }
        float4 w;
        float* wp = (float*)&w;
#pragma unroll
        for (int e = 0; e < 4; ++e) {
            float v = fmaxf(s[e] * (1.0f / C), 1e-7f);
            wp[e] = (t0 + e < T0) ? 0.f : rsqrtf(v);   // sqrt(1/power)
        }
        *(float4*)(W + (size_t)bf * T + t0) = w;
    }
}

// ---------------- kernel 2: R,P via bf16 MFMA — 4 waves/block (best measured) ----------------
#define WB 10624

__global__ __launch_bounds__(256, 3) void rp_mfma_kernel(const float* __restrict__ mr,
                                                         const float* __restrict__ mi,
                                                         const float* __restrict__ W,
                                                         float2* __restrict__ Rout,
                                                         float2* __restrict__ Pout) {
    __shared__ __align__(16) unsigned char SH[4 * WB];
    const int lane = threadIdx.x & 63;
    const int wid = threadIdx.x >> 6;
    const int bf = blockIdx.x * 4 + wid;
    unsigned char* base = SH + wid * WB;
    float* sre = (float*)(base + 7680);
    float* sim_ = (float*)(base + 9088);
    float* wsh = (float*)(base + 10496);

    const float* mrp = mr + (size_t)bf * C * T;
    const float* mip = mi + (size_t)bf * C * T;
    const float* Wp  = W  + (size_t)bf * T;

    const int q = lane >> 4, col = lane & 15;
    const int pc = lane >> 3, pg = lane & 7;     // phase-B task: channel, 4t-group

    const int PM[6] = {0, 0, 0, 1, 1, 2};
    const int PN[6] = {0, 1, 2, 1, 2, 2};

    f32x4 accRe[6], accIr[6], accRi[6];
#pragma unroll
    for (int p = 0; p < 6; ++p) {
        accRe[p] = (f32x4){0.f, 0.f, 0.f, 0.f};
        accIr[p] = (f32x4){0.f, 0.f, 0.f, 0.f};
        accRi[p] = (f32x4){0.f, 0.f, 0.f, 0.f};
    }

    for (int ks = 0; ks < 25; ++ks) {
        const int tb = ks * 32;

        // ---- Phase A: vectorized global -> fp32 LDS scratch ----
#pragma unroll
        for (int it = 0; it < 3; ++it) {
            int task = lane + it * 64;
            if (task < 160) {
                int pl = task / 80;
                int rem = task - pl * 80;
                int c = rem / 10, grp = rem - c * 10;
                int tg = tb - 8 + grp * 4;
                const float* srcp = pl ? mip : mrp;
                float4 v = make_float4(0.f, 0.f, 0.f, 0.f);
                if (tg >= 0) v = *(const float4*)(srcp + c * T + tg);
                *(float4*)((pl ? sim_ : sre) + c * 44 + grp * 4) = v;
            } else if (task < 168) {
                int grp = task - 160;
                *(float4*)(wsh + grp * 4) = *(const float4*)(Wp + tb + grp * 4);
            }
        }

        // ---- Phase B: build 6 shift-variant bf16 rows from scratch ----
        {
            float yre[12], yim[12];
            int ybase = pc * 44 + pg * 4;
#pragma unroll
            for (int i = 1; i <= 11; ++i) {
                yre[i] = sre[ybase + i];
                yim[i] = sim_[ybase + i];
            }
            float4 w4 = *(const float4*)(wsh + pg * 4);
            float wv[4] = {w4.x, w4.y, w4.z, w4.w};
#pragma unroll
            for (int v = 0; v < 6; ++v) {
                int row = (v < 5) ? (v * 8 + pc) : (40 + pc);
                int off = (v < 5) ? (5 - v) : 8;
                bf16x4 zr, zi;
#pragma unroll
                for (int e = 0; e < 4; ++e) {
                    zr[e] = (__bf16)(wv[e] * yre[off + e]);
                    zi[e] = (__bf16)(wv[e] * yim[off + e]);
                }
                *(bf16x4*)(base + row * 80 + pg * 8) = zr;
                *(bf16x4*)(base + 3840 + row * 80 + pg * 8) = zi;
            }
        }

        // ---- fragments (shared A/B operand) + 24 MFMA ----
        bf16x8 fr[3], fi[3];
#pragma unroll
        for (int X = 0; X < 3; ++X) {
            fr[X] = *(const bf16x8*)(base + (X * 16 + col) * 80 + q * 16);
            fi[X] = *(const bf16x8*)(base + 3840 + (X * 16 + col) * 80 + q * 16);
        }
#pragma unroll
        for (int p = 0; p < 6; ++p) {
            int mt = PM[p], nt = PN[p];
            accRe[p] = __builtin_amdgcn_mfma_f32_16x16x32_bf16(fr[mt], fr[nt], accRe[p], 0, 0, 0);
            accRe[p] = __builtin_amdgcn_mfma_f32_16x16x32_bf16(fi[mt], fi[nt], accRe[p], 0, 0, 0);
            accIr[p] = __builtin_amdgcn_mfma_f32_16x16x32_bf16(fi[mt], fr[nt], accIr[p], 0, 0, 0);
            accRi[p] = __builtin_amdgcn_mfma_f32_16x16x32_bf16(fr[mt], fi[nt], accRi[p], 0, 0, 0);
        }
    }

    // ---- epilogue: D row=(lane>>4)*4+reg, col=lane&15 (m89); Hermitian mirror ----
    // EPS_REG added on the diagonal here.
    float2* Rp = Rout + (size_t)bf * K * K;
    float2* Pp = Pout + (size_t)bf * K * C;
#pragma unroll
    for (int p = 0; p < 6; ++p) {
        int mt = PM[p], nt = PN[p];
#pragma unroll
        for (int r = 0; r < 4; ++r) {
            int m = mt * 16 + q * 4 + r;
            int n = nt * 16 + col;
            float re = accRe[p][r];
            float im = accIr[p][r] - accRi[p][r];
            if (m < K) {
                if (n < K) {
                    if (m == n) re += 1e-10f;
                    Rp[m * K + n] = make_float2(re, im);
                } else {
                    Pp[m * C + (n - K)] = make_float2(re, im);
                }
            }
            if (mt != nt && m < K && n < K)
                Rp[n * K + m] = make_float2(re, -im);
        }
    }
}

// ---------------- kernel 3: solve R G = P — rolled GJ with register rotation ----------------
// One wave per bf. Lane i holds row i of [R|P] in 48 float2 registers.
// Rolled j-loop (I-cache friendly: ~9 KB body vs 60 KB full unroll):
// invariant at step j: rotated index i == original column j+i. Eliminate with
// index 0 (pivot col j, pivot lane j via dynamic readlane), update indices
// 1..U-1 (U static per phase: 48/38/28/18), then shift row[m]=row[m+1] (static
// indices -> stays in registers, rule #20). After 40 steps RHS sits at 0..7.
__device__ __forceinline__ float rdlane(float v, int j) {
    return __uint_as_float(__builtin_amdgcn_readlane(__float_as_uint(v), (unsigned)j));
}

__global__ __launch_bounds__(64) void solve_kernel(const float2* __restrict__ Rin,
                                                   const float2* __restrict__ Pin,
                                                   float2* __restrict__ Gout) {
    const int bf = blockIdx.x;
    const int lane = threadIdx.x;
    const bool act = lane < K;

    float2 row[NCOL];
    {
        const float4* Rp4 = (const float4*)(Rin + (size_t)bf * K * K + (size_t)(act ? lane : 0) * K);
        const float4* Pp4 = (const float4*)(Pin + (size_t)bf * K * C + (size_t)(act ? lane : 0) * C);
#pragma unroll
        for (int m = 0; m < K / 2; ++m) {
            float4 v = Rp4[m];
            if (!act) v = make_float4(0.f, 0.f, 0.f, 0.f);
            row[2 * m]     = make_float2(v.x, v.y);
            row[2 * m + 1] = make_float2(v.z, v.w);
        }
#pragma unroll
        for (int m = 0; m < C / 2; ++m) {
            float4 v = Pp4[m];
            if (!act) v = make_float4(0.f, 0.f, 0.f, 0.f);
            row[K + 2 * m]     = make_float2(v.x, v.y);
            row[K + 2 * m + 1] = make_float2(v.z, v.w);
        }
    }

    int j = 0;
#pragma unroll
    for (int phase = 0; phase < 4; ++phase) {
        const int U = NCOL - phase * 10;   // 48, 38, 28, 18 — static per phase
#pragma unroll 1
        for (int s = 0; s < 10; ++s, ++j) {
            // pivot d = original A[j][j] = rotated index 0, lane j
            float dx = rdlane(row[0].x, j);
            float dy = rdlane(row[0].y, j);
            float den = fmaf(dx, dx, dy * dy);
            float r = __builtin_amdgcn_rcpf(den);
            float ix = dx * r;          // invd = conj(d)/|d|^2
            float iy = -dy * r;
            // multiplier l = row[0]*invd; lane j: l = 1 - invd (normalizes row j)
            float lx = row[0].x * ix - row[0].y * iy;
            float ly = row[0].x * iy + row[0].y * ix;
            bool isj = (lane == j);
            lx = isj ? (1.0f - ix) : lx;
            ly = isj ? (0.0f - iy) : ly;
#pragma unroll
            for (int n = 1; n < U; ++n) {
                float ux = rdlane(row[n].x, j);
                float uy = rdlane(row[n].y, j);
                row[n].x = fmaf(-lx, ux, fmaf( ly, uy, row[n].x));
                row[n].y = fmaf(-lx, uy, fmaf(-ly, ux, row[n].y));
            }
            // rotate left (pivot column dropped); static indices keep regs
#pragma unroll
            for (int m = 0; m + 1 < U; ++m) row[m] = row[m + 1];
        }
    }

    if (act) {
        // RHS columns (orig 40..47) now at rotated indices 0..7
        float4* Gp = (float4*)(Gout + (size_t)bf * K * C + (size_t)lane * C);
#pragma unroll
        for (int m = 0; m < C / 2; ++m)
            Gp[m] = make_float4(row[2 * m].x, row[2 * m].y,
                                row[2 * m + 1].x, row[2 * m + 1].y);
    }
}

// ---------------- kernel 4: X via bf16 MFMA — prefetch + epilogue-Y-from-LDS ----------------
#define XSTR 144
#define XWB 12032

__device__ __forceinline__ PF x_load(const float* __restrict__ mrp,
                                     const float* __restrict__ mip,
                                     int tb, int lane) {
    PF p;
#pragma unroll
    for (int it = 0; it < 3; ++it) {
        int task = lane + it * 64;
        float4 v = make_float4(0.f, 0.f, 0.f, 0.f);
        if (task < 160) {
            int pl = task / 80;
            int rem = task - pl * 80;
            int c = rem / 10, grp = rem - c * 10;
            int tg = tb - 8 + grp * 4;
            const float* srcp = pl ? mip : mrp;
            if (tg >= 0) v = *(const float4*)(srcp + c * T + tg);
        }
        p.v[it] = v;
    }
    return p;
}

__device__ __forceinline__ void x_store(const PF& p, float* sre, float* sim_, int lane) {
#pragma unroll
    for (int it = 0; it < 3; ++it) {
        int task = lane + it * 64;
        if (task < 160) {
            int pl = task / 80;
            int rem = task - pl * 80;
            int c = rem / 10, grp = rem - c * 10;
            *(float4*)((pl ? sim_ : sre) + c * 44 + grp * 4) = p.v[it];
        }
    }
}

__global__ __launch_bounds__(64) void x_mfma_kernel(const float* __restrict__ mr,
                                                    const float* __restrict__ mi,
                                                    const float2* __restrict__ Gin,
                                                    const int* __restrict__ ilens,
                                                    float2* __restrict__ out) {
    __shared__ __align__(16) unsigned char SH[XWB];
    const int lane = threadIdx.x;
    const int gid = blockIdx.x;
    const int bf = gid >> 2;
    const int split = gid & 3;
    const int ck0 = (split == 0) ? 0 : (1 + split * 6);
    const int nck = (split == 0) ? 7 : 6;
    unsigned char* base = SH;
    float* sre = (float*)(base + 9216);
    float* sim_ = (float*)(base + 10624);

    const float* mrp = mr + (size_t)bf * C * T;
    const float* mip = mi + (size_t)bf * C * T;
    const float2* Gp = Gin + (size_t)bf * K * C;
    float2* outp = out + (size_t)bf * C * T;
    const int len = ilens[bf / F];

    const int q = lane >> 4, col = lane & 15;
    const int t2 = lane >> 1, half = lane & 1;

    // ---- one-time: zero-fill bytes [80,128) of all rows (a = 40..63 -> 0.0) ----
#pragma unroll
    for (int pl = 0; pl < 2; ++pl) {
        unsigned char* pb = base + pl * 4608 + t2 * XSTR + 80 + half * 24;
        *(float2*)(pb)      = make_float2(0.f, 0.f);
        *(float2*)(pb + 8)  = make_float2(0.f, 0.f);
        *(float2*)(pb + 16) = make_float2(0.f, 0.f);
    }

    // ---- A fragments: G (and -Gi) in registers, built once ----
    bf16x8 Agr[2], Agi[2], Agin[2];
#pragma unroll
    for (int ks = 0; ks < 2; ++ks)
#pragma unroll
        for (int j = 0; j < 8; ++j) {
            int a = ks * 32 + q * 8 + j;
            float2 g = make_float2(0.f, 0.f);
            if (a < K && col < C) g = Gp[a * C + col];
            Agr[ks][j]  = (__bf16)g.x;
            Agi[ks][j]  = (__bf16)g.y;
            Agin[ks][j] = (__bf16)(-g.y);
        }

    PF cur = x_load(mrp, mip, ck0 * 32, lane);

    for (int ci = 0; ci < nck; ++ci) {
        const int tb = (ck0 + ci) * 32;

        // ---- write staged chunk; prefetch next ----
        x_store(cur, sre, sim_, lane);
        if (ci + 1 < nck) cur = x_load(mrp, mip, tb + 32, lane);

        // ---- Phase B: build transposed bf16 Ytilde rows [t_local][a] ----
#pragma unroll
        for (int i = 0; i < 5; ++i) {
            int abase = half * 20 + 4 * i;
            bf16x4 zr, zi;
#pragma unroll
            for (int e2 = 0; e2 < 4; ++e2) {
                int a = abase + e2;
                int v = a >> 3, c = a & 7;
                int idx = c * 44 + t2 + 5 - v;   // Y[c][tb+t2-3-v]
                zr[e2] = (__bf16)sre[idx];
                zi[e2] = (__bf16)sim_[idx];
            }
            *(bf16x4*)(base + t2 * XSTR + abase * 2) = zr;
            *(bf16x4*)(base + 4608 + t2 * XSTR + abase * 2) = zi;
        }

        // ---- two 16-t tiles: 8 MFMA each + epilogue (Y from scratch LDS) ----
#pragma unroll
        for (int tt = 0; tt < 2; ++tt) {
            const int trow = tt * 16 + col;
            f32x4 accRe = (f32x4){0.f, 0.f, 0.f, 0.f};
            f32x4 accIm = (f32x4){0.f, 0.f, 0.f, 0.f};
#pragma unroll
            for (int ks = 0; ks < 2; ++ks) {
                bf16x8 byr = *(const bf16x8*)(base + trow * XSTR + ks * 64 + q * 16);
                bf16x8 byi = *(const bf16x8*)(base + 4608 + trow * XSTR + ks * 64 + q * 16);
                accRe = __builtin_amdgcn_mfma_f32_16x16x32_bf16(Agr[ks], byr, accRe, 0, 0, 0);
                accRe = __builtin_amdgcn_mfma_f32_16x16x32_bf16(Agi[ks], byi, accRe, 0, 0, 0);
                accIm = __builtin_amdgcn_mfma_f32_16x16x32_bf16(Agr[ks], byi, accIm, 0, 0, 0);
                accIm = __builtin_amdgcn_mfma_f32_16x16x32_bf16(Agin[ks], byr, accIm, 0, 0, 0);
            }
            // D row=(lane>>4)*4+r (=e), col=lane&15 (=t offset) [m89]
            if (q < 2) {
                int t = tb + tt * 16 + col;
                int l = tt * 16 + col + 8;       // scratch index of t
                bool ok = (t < len);
#pragma unroll
                for (int r = 0; r < 4; ++r) {
                    int e = q * 4 + r;
                    float yr = sre[e * 44 + l];
                    float yi = sim_[e * 44 + l];
                    float2 v = ok ? make_float2(yr - accRe[r], yi - accIm[r])
                                  : make_float2(0.f, 0.f);
                    outp[e * T + t] = v;
                }
            }
        }
    }
}

extern "C" void kernel_launch(void* const* d_in, const int* in_sizes, int n_in,
                              void* d_out, int out_size, void* d_ws, size_t ws_size,
                              hipStream_t stream) {
    const float* sep_r = (const float*)d_in[0];
    const float* sep_i = (const float*)d_in[1];
    const float* mix_r = (const float*)d_in[2];
    const float* mix_i = (const float*)d_in[3];
    const int* ilens   = (const int*)d_in[4];

    float* ws = (float*)d_ws;
    float* W = ws;                                        // BF*T floats
    float2* Rws = (float2*)(ws + (size_t)BF * T);         // BF*K*K float2
    float2* Gws = Rws + (size_t)BF * K * K;               // BF*K*C float2 (P then G in-place)

    power_kernel<<<BF, 256, 0, stream>>>(sep_r, sep_i, W);
    rp_mfma_kernel<<<BF / 4, 256, 0, stream>>>(mix_r, mix_i, W, Rws, Gws);
    solve_kernel<<<BF, 64, 0, stream>>>(Rws, Gws, Gws);
    x_mfma_kernel<<<BF * 4, 64, 0, stream>>>(mix_r, mix_i, Gws, ilens, (float2*)d_out);
}

// Round 19
// 186.965 us; speedup vs baseline: 1.0955x; 1.0955x over previous
//
#include <hip/hip_runtime.h>

#define B 8
#define F 257
#define C 8
#define T 800
#define TAPS 5
#define DELAY 3
#define K 40         // TAPS*C
#define NCOL 48      // K + C
#define T0 7         // DELAY + TAPS - 1
#define BF (B*F)     // 2056

typedef __bf16 bf16x8 __attribute__((ext_vector_type(8)));
typedef __bf16 bf16x4 __attribute__((ext_vector_type(4)));
typedef float f32x4 __attribute__((ext_vector_type(4)));

struct PF { float4 v[3]; };

// ---------------- kernel 1: sqrt inverse power weights (0 for t<T0) ----------------
__global__ __launch_bounds__(256) void power_kernel(const float* __restrict__ sr,
                                                    const float* __restrict__ si,
                                                    float* __restrict__ W) {
    int bf = blockIdx.x;
    const float* srp = sr + (size_t)bf * C * T;
    const float* sip = si + (size_t)bf * C * T;
    int t0 = threadIdx.x * 4;
    if (t0 < T) {
        float s[4] = {0.f, 0.f, 0.f, 0.f};
#pragma unroll
        for (int c = 0; c < C; ++c) {
            float4 a = *(const float4*)(srp + c * T + t0);
            float4 b = *(const float4*)(sip + c * T + t0);
            s[0] = fmaf(a.x, a.x, fmaf(b.x, b.x, s[0]));
            s[1] = fmaf(a.y, a.y, fmaf(b.y, b.y, s[1]));
            s[2] = fmaf(a.z, a.z, fmaf(b.z, b.z, s[2]));
            s[3] = fmaf(a.w, a.w, fmaf(b.w, b.w, s[3]));
        }
        float4 w;
        float* wp = (float*)&w;
#pragma unroll
        for (int e = 0; e < 4; ++e) {
            float v = fmaxf(s[e] * (1.0f / C), 1e-7f);
            wp[e] = (t0 + e < T0) ? 0.f : rsqrtf(v);   // sqrt(1/power)
        }
        *(float4*)(W + (size_t)bf * T + t0) = w;
    }
}

// ---------------- kernel 2: R,P via bf16 MFMA — 4 waves/block, b128 Phase-B reads ----------------
#define WB 10624

__global__ __launch_bounds__(256, 3) void rp_mfma_kernel(const float* __restrict__ mr,
                                                         const float* __restrict__ mi,
                                                         const float* __restrict__ W,
                                                         float2* __restrict__ Rout,
                                                         float2* __restrict__ Pout) {
    __shared__ __align__(16) unsigned char SH[4 * WB];
    const int lane = threadIdx.x & 63;
    const int wid = threadIdx.x >> 6;
    const int bf = blockIdx.x * 4 + wid;
    unsigned char* base = SH + wid * WB;
    float* sre = (float*)(base + 7680);
    float* sim_ = (float*)(base + 9088);
    float* wsh = (float*)(base + 10496);

    const float* mrp = mr + (size_t)bf * C * T;
    const float* mip = mi + (size_t)bf * C * T;
    const float* Wp  = W  + (size_t)bf * T;

    const int q = lane >> 4, col = lane & 15;
    const int pc = lane >> 3, pg = lane & 7;     // phase-B task: channel, 4t-group

    const int PM[6] = {0, 0, 0, 1, 1, 2};
    const int PN[6] = {0, 1, 2, 1, 2, 2};

    f32x4 accRe[6], accIr[6], accRi[6];
#pragma unroll
    for (int p = 0; p < 6; ++p) {
        accRe[p] = (f32x4){0.f, 0.f, 0.f, 0.f};
        accIr[p] = (f32x4){0.f, 0.f, 0.f, 0.f};
        accRi[p] = (f32x4){0.f, 0.f, 0.f, 0.f};
    }

    for (int ks = 0; ks < 25; ++ks) {
        const int tb = ks * 32;

        // ---- Phase A: vectorized global -> fp32 LDS scratch ----
#pragma unroll
        for (int it = 0; it < 3; ++it) {
            int task = lane + it * 64;
            if (task < 160) {
                int pl = task / 80;
                int rem = task - pl * 80;
                int c = rem / 10, grp = rem - c * 10;
                int tg = tb - 8 + grp * 4;
                const float* srcp = pl ? mip : mrp;
                float4 v = make_float4(0.f, 0.f, 0.f, 0.f);
                if (tg >= 0) v = *(const float4*)(srcp + c * T + tg);
                *(float4*)((pl ? sim_ : sre) + c * 44 + grp * 4) = v;
            } else if (task < 168) {
                int grp = task - 160;
                *(float4*)(wsh + grp * 4) = *(const float4*)(Wp + tb + grp * 4);
            }
        }

        // ---- Phase B: build 6 shift-variant bf16 rows (b128 scratch reads) ----
        {
            int ybase = pc * 44 + pg * 4;   // multiple of 4 floats -> 16B aligned
            float yre[12], yim[12];
            float4 r0 = *(const float4*)(sre + ybase);
            float4 r1 = *(const float4*)(sre + ybase + 4);
            float4 r2 = *(const float4*)(sre + ybase + 8);
            float4 i0 = *(const float4*)(sim_ + ybase);
            float4 i1 = *(const float4*)(sim_ + ybase + 4);
            float4 i2 = *(const float4*)(sim_ + ybase + 8);
            yre[0] = r0.x; yre[1] = r0.y; yre[2]  = r0.z; yre[3]  = r0.w;
            yre[4] = r1.x; yre[5] = r1.y; yre[6]  = r1.z; yre[7]  = r1.w;
            yre[8] = r2.x; yre[9] = r2.y; yre[10] = r2.z; yre[11] = r2.w;
            yim[0] = i0.x; yim[1] = i0.y; yim[2]  = i0.z; yim[3]  = i0.w;
            yim[4] = i1.x; yim[5] = i1.y; yim[6]  = i1.z; yim[7]  = i1.w;
            yim[8] = i2.x; yim[9] = i2.y; yim[10] = i2.z; yim[11] = i2.w;
            float4 w4 = *(const float4*)(wsh + pg * 4);
            float wv[4] = {w4.x, w4.y, w4.z, w4.w};
#pragma unroll
            for (int v = 0; v < 6; ++v) {
                int row = (v < 5) ? (v * 8 + pc) : (40 + pc);
                int off = (v < 5) ? (5 - v) : 8;
                bf16x4 zr, zi;
#pragma unroll
                for (int e = 0; e < 4; ++e) {
                    zr[e] = (__bf16)(wv[e] * yre[off + e]);
                    zi[e] = (__bf16)(wv[e] * yim[off + e]);
                }
                *(bf16x4*)(base + row * 80 + pg * 8) = zr;
                *(bf16x4*)(base + 3840 + row * 80 + pg * 8) = zi;
            }
        }

        // ---- fragments (shared A/B operand) + 24 MFMA ----
        bf16x8 fr[3], fi[3];
#pragma unroll
        for (int X = 0; X < 3; ++X) {
            fr[X] = *(const bf16x8*)(base + (X * 16 + col) * 80 + q * 16);
            fi[X] = *(const bf16x8*)(base + 3840 + (X * 16 + col) * 80 + q * 16);
        }
#pragma unroll
        for (int p = 0; p < 6; ++p) {
            int mt = PM[p], nt = PN[p];
            accRe[p] = __builtin_amdgcn_mfma_f32_16x16x32_bf16(fr[mt], fr[nt], accRe[p], 0, 0, 0);
            accRe[p] = __builtin_amdgcn_mfma_f32_16x16x32_bf16(fi[mt], fi[nt], accRe[p], 0, 0, 0);
            accIr[p] = __builtin_amdgcn_mfma_f32_16x16x32_bf16(fi[mt], fr[nt], accIr[p], 0, 0, 0);
            accRi[p] = __builtin_amdgcn_mfma_f32_16x16x32_bf16(fr[mt], fi[nt], accRi[p], 0, 0, 0);
        }
    }

    // ---- epilogue: D row=(lane>>4)*4+reg, col=lane&15 (m89); Hermitian mirror ----
    // EPS_REG added on the diagonal here.
    float2* Rp = Rout + (size_t)bf * K * K;
    float2* Pp = Pout + (size_t)bf * K * C;
#pragma unroll
    for (int p = 0; p < 6; ++p) {
        int mt = PM[p], nt = PN[p];
#pragma unroll
        for (int r = 0; r < 4; ++r) {
            int m = mt * 16 + q * 4 + r;
            int n = nt * 16 + col;
            float re = accRe[p][r];
            float im = accIr[p][r] - accRi[p][r];
            if (m < K) {
                if (n < K) {
                    if (m == n) re += 1e-10f;
                    Rp[m * K + n] = make_float2(re, im);
                } else {
                    Pp[m * C + (n - K)] = make_float2(re, im);
                }
            }
            if (mt != nt && m < K && n < K)
                Rp[n * K + m] = make_float2(re, -im);
        }
    }
}

// ---------------- kernel 3: solve R G = P — register GJ, high-VGPR launch bounds ----------------
// One wave per bf; grid needs only 8 waves/CU, so allow up to 2 waves/EU -> VGPR cap 256:
// row[48] float2 (96 VGPR) now lives in true VGPRs (no AGPR shuffling / allocation squeeze).
__device__ __forceinline__ float rdlane(float v, int j) {
    return __uint_as_float(__builtin_amdgcn_readlane(__float_as_uint(v), (unsigned)j));
}

__global__ __launch_bounds__(64, 2) void solve_kernel(const float2* __restrict__ Rin,
                                                      const float2* __restrict__ Pin,
                                                      float2* __restrict__ Gout) {
    const int bf = blockIdx.x;
    const int lane = threadIdx.x;
    const bool act = lane < K;

    float2 row[NCOL];
    {
        const float4* Rp4 = (const float4*)(Rin + (size_t)bf * K * K + (size_t)(act ? lane : 0) * K);
        const float4* Pp4 = (const float4*)(Pin + (size_t)bf * K * C + (size_t)(act ? lane : 0) * C);
#pragma unroll
        for (int m = 0; m < K / 2; ++m) {
            float4 v = Rp4[m];
            if (!act) v = make_float4(0.f, 0.f, 0.f, 0.f);
            row[2 * m]     = make_float2(v.x, v.y);
            row[2 * m + 1] = make_float2(v.z, v.w);
        }
#pragma unroll
        for (int m = 0; m < C / 2; ++m) {
            float4 v = Pp4[m];
            if (!act) v = make_float4(0.f, 0.f, 0.f, 0.f);
            row[K + 2 * m]     = make_float2(v.x, v.y);
            row[K + 2 * m + 1] = make_float2(v.z, v.w);
        }
    }

#pragma unroll
    for (int j = 0; j < K; ++j) {
        float dx = rdlane(row[j].x, j);
        float dy = rdlane(row[j].y, j);
        float den = fmaf(dx, dx, dy * dy);
        float r = 1.0f / den;
        float ix = dx * r;
        float iy = -dy * r;
        float lx = row[j].x * ix - row[j].y * iy;
        float ly = row[j].x * iy + row[j].y * ix;
        bool isj = (lane == j);
        lx = isj ? (1.0f - ix) : lx;
        ly = isj ? (0.0f - iy) : ly;
#pragma unroll
        for (int n = j; n < NCOL; ++n) {
            float ux = rdlane(row[n].x, j);
            float uy = rdlane(row[n].y, j);
            row[n].x = fmaf(-lx, ux, fmaf( ly, uy, row[n].x));
            row[n].y = fmaf(-lx, uy, fmaf(-ly, ux, row[n].y));
        }
    }

    if (act) {
        float4* Gp = (float4*)(Gout + (size_t)bf * K * C + (size_t)lane * C);
#pragma unroll
        for (int m = 0; m < C / 2; ++m)
            Gp[m] = make_float4(row[K + 2 * m].x, row[K + 2 * m].y,
                                row[K + 2 * m + 1].x, row[K + 2 * m + 1].y);
    }
}

// ---------------- kernel 4: X via bf16 MFMA — prefetch + epilogue-Y-from-LDS ----------------
#define XSTR 144
#define XWB 12032

__device__ __forceinline__ PF x_load(const float* __restrict__ mrp,
                                     const float* __restrict__ mip,
                                     int tb, int lane) {
    PF p;
#pragma unroll
    for (int it = 0; it < 3; ++it) {
        int task = lane + it * 64;
        float4 v = make_float4(0.f, 0.f, 0.f, 0.f);
        if (task < 160) {
            int pl = task / 80;
            int rem = task - pl * 80;
            int c = rem / 10, grp = rem - c * 10;
            int tg = tb - 8 + grp * 4;
            const float* srcp = pl ? mip : mrp;
            if (tg >= 0) v = *(const float4*)(srcp + c * T + tg);
        }
        p.v[it] = v;
    }
    return p;
}

__device__ __forceinline__ void x_store(const PF& p, float* sre, float* sim_, int lane) {
#pragma unroll
    for (int it = 0; it < 3; ++it) {
        int task = lane + it * 64;
        if (task < 160) {
            int pl = task / 80;
            int rem = task - pl * 80;
            int c = rem / 10, grp = rem - c * 10;
            *(float4*)((pl ? sim_ : sre) + c * 44 + grp * 4) = p.v[it];
        }
    }
}

__global__ __launch_bounds__(64) void x_mfma_kernel(const float* __restrict__ mr,
                                                    const float* __restrict__ mi,
                                                    const float2* __restrict__ Gin,
                                                    const int* __restrict__ ilens,
                                                    float2* __restrict__ out) {
    __shared__ __align__(16) unsigned char SH[XWB];
    const int lane = threadIdx.x;
    const int gid = blockIdx.x;
    const int bf = gid >> 2;
    const int split = gid & 3;
    const int ck0 = (split == 0) ? 0 : (1 + split * 6);
    const int nck = (split == 0) ? 7 : 6;
    unsigned char* base = SH;
    float* sre = (float*)(base + 9216);
    float* sim_ = (float*)(base + 10624);

    const float* mrp = mr + (size_t)bf * C * T;
    const float* mip = mi + (size_t)bf * C * T;
    const float2* Gp = Gin + (size_t)bf * K * C;
    float2* outp = out + (size_t)bf * C * T;
    const int len = ilens[bf / F];

    const int q = lane >> 4, col = lane & 15;
    const int t2 = lane >> 1, half = lane & 1;

    // ---- one-time: zero-fill bytes [80,128) of all rows (a = 40..63 -> 0.0) ----
#pragma unroll
    for (int pl = 0; pl < 2; ++pl) {
        unsigned char* pb = base + pl * 4608 + t2 * XSTR + 80 + half * 24;
        *(float2*)(pb)      = make_float2(0.f, 0.f);
        *(float2*)(pb + 8)  = make_float2(0.f, 0.f);
        *(float2*)(pb + 16) = make_float2(0.f, 0.f);
    }

    // ---- A fragments: G (and -Gi) in registers, built once ----
    bf16x8 Agr[2], Agi[2], Agin[2];
#pragma unroll
    for (int ks = 0; ks < 2; ++ks)
#pragma unroll
        for (int j = 0; j < 8; ++j) {
            int a = ks * 32 + q * 8 + j;
            float2 g = make_float2(0.f, 0.f);
            if (a < K && col < C) g = Gp[a * C + col];
            Agr[ks][j]  = (__bf16)g.x;
            Agi[ks][j]  = (__bf16)g.y;
            Agin[ks][j] = (__bf16)(-g.y);
        }

    PF cur = x_load(mrp, mip, ck0 * 32, lane);

    for (int ci = 0; ci < nck; ++ci) {
        const int tb = (ck0 + ci) * 32;

        // ---- write staged chunk; prefetch next ----
        x_store(cur, sre, sim_, lane);
        if (ci + 1 < nck) cur = x_load(mrp, mip, tb + 32, lane);

        // ---- Phase B: build transposed bf16 Ytilde rows [t_local][a] ----
#pragma unroll
        for (int i = 0; i < 5; ++i) {
            int abase = half * 20 + 4 * i;
            bf16x4 zr, zi;
#pragma unroll
            for (int e2 = 0; e2 < 4; ++e2) {
                int a = abase + e2;
                int v = a >> 3, c = a & 7;
                int idx = c * 44 + t2 + 5 - v;   // Y[c][tb+t2-3-v]
                zr[e2] = (__bf16)sre[idx];
                zi[e2] = (__bf16)sim_[idx];
            }
            *(bf16x4*)(base + t2 * XSTR + abase * 2) = zr;
            *(bf16x4*)(base + 4608 + t2 * XSTR + abase * 2) = zi;
        }

        // ---- two 16-t tiles: 8 MFMA each + epilogue (Y from scratch LDS) ----
#pragma unroll
        for (int tt = 0; tt < 2; ++tt) {
            const int trow = tt * 16 + col;
            f32x4 accRe = (f32x4){0.f, 0.f, 0.f, 0.f};
            f32x4 accIm = (f32x4){0.f, 0.f, 0.f, 0.f};
#pragma unroll
            for (int ks = 0; ks < 2; ++ks) {
                bf16x8 byr = *(const bf16x8*)(base + trow * XSTR + ks * 64 + q * 16);
                bf16x8 byi = *(const bf16x8*)(base + 4608 + trow * XSTR + ks * 64 + q * 16);
                accRe = __builtin_amdgcn_mfma_f32_16x16x32_bf16(Agr[ks], byr, accRe, 0, 0, 0);
                accRe = __builtin_amdgcn_mfma_f32_16x16x32_bf16(Agi[ks], byi, accRe, 0, 0, 0);
                accIm = __builtin_amdgcn_mfma_f32_16x16x32_bf16(Agr[ks], byi, accIm, 0, 0, 0);
                accIm = __builtin_amdgcn_mfma_f32_16x16x32_bf16(Agin[ks], byr, accIm, 0, 0, 0);
            }
            // D row=(lane>>4)*4+r (=e), col=lane&15 (=t offset) [m89]
            if (q < 2) {
                int t = tb + tt * 16 + col;
                int l = tt * 16 + col + 8;       // scratch index of t
                bool ok = (t < len);
#pragma unroll
                for (int r = 0; r < 4; ++r) {
                    int e = q * 4 + r;
                    float yr = sre[e * 44 + l];
                    float yi = sim_[e * 44 + l];
                    float2 v = ok ? make_float2(yr - accRe[r], yi - accIm[r])
                                  : make_float2(0.f, 0.f);
                    outp[e * T + t] = v;
                }
            }
        }
    }
}

extern "C" void kernel_launch(void* const* d_in, const int* in_sizes, int n_in,
                              void* d_out, int out_size, void* d_ws, size_t ws_size,
                              hipStream_t stream) {
    const float* sep_r = (const float*)d_in[0];
    const float* sep_i = (const float*)d_in[1];
    const float* mix_r = (const float*)d_in[2];
    const float* mix_i = (const float*)d_in[3];
    const int* ilens   = (const int*)d_in[4];

    float* ws = (float*)d_ws;
    float* W = ws;                                        // BF*T floats
    float2* Rws = (float2*)(ws + (size_t)BF * T);         // BF*K*K float2
    float2* Gws = Rws + (size_t)BF * K * K;               // BF*K*C float2 (P then G in-place)

    power_kernel<<<BF, 256, 0, stream>>>(sep_r, sep_i, W);
    rp_mfma_kernel<<<BF / 4, 256, 0, stream>>>(mix_r, mix_i, W, Rws, Gws);
    solve_kernel<<<BF, 64, 0, stream>>>(Rws, Gws, Gws);
    x_mfma_kernel<<<BF * 4, 64, 0, stream>>>(mix_r, mix_i, Gws, ilens, (float2*)d_out);
}

// Round 21
// 181.259 us; speedup vs baseline: 1.1300x; 1.0315x over previous
//
#include <hip/hip_runtime.h>

#define B 8
#define F 257
#define C 8
#define T 800
#define TAPS 5
#define DELAY 3
#define K 40         // TAPS*C
#define NCOL 48      // K + C
#define T0 7         // DELAY + TAPS - 1
#define BF (B*F)     // 2056

typedef __bf16 bf16x8 __attribute__((ext_vector_type(8)));
typedef __bf16 bf16x4 __attribute__((ext_vector_type(4)));
typedef float f32x4 __attribute__((ext_vector_type(4)));

struct PF { float4 v[3]; };

__device__ __forceinline__ void dma16(const void* g, void* l) {
    __builtin_amdgcn_global_load_lds(
        (const __attribute__((address_space(1))) void*)g,
        (__attribute__((address_space(3))) void*)l, 16, 0, 0);
}

// ---------------- kernel 1: sqrt inverse power weights (0 for t<T0) ----------------
__global__ __launch_bounds__(256) void power_kernel(const float* __restrict__ sr,
                                                    const float* __restrict__ si,
                                                    float* __restrict__ W) {
    int bf = blockIdx.x;
    const float* srp = sr + (size_t)bf * C * T;
    const float* sip = si + (size_t)bf * C * T;
    int t0 = threadIdx.x * 4;
    if (t0 < T) {
        float s[4] = {0.f, 0.f, 0.f, 0.f};
#pragma unroll
        for (int c = 0; c < C; ++c) {
            float4 a = *(const float4*)(srp + c * T + t0);
            float4 b = *(const float4*)(sip + c * T + t0);
            s[0] = fmaf(a.x, a.x, fmaf(b.x, b.x, s[0]));
            s[1] = fmaf(a.y, a.y, fmaf(b.y, b.y, s[1]));
            s[2] = fmaf(a.z, a.z, fmaf(b.z, b.z, s[2]));
            s[3] = fmaf(a.w, a.w, fmaf(b.w, b.w, s[3]));
        }
        float4 w;
        float* wp = (float*)&w;
#pragma unroll
        for (int e = 0; e < 4; ++e) {
            float v = fmaxf(s[e] * (1.0f / C), 1e-7f);
            wp[e] = (t0 + e < T0) ? 0.f : rsqrtf(v);   // sqrt(1/power)
        }
        *(float4*)(W + (size_t)bf * T + t0) = w;
    }
}

// ---------------- kernel 2: R,P via bf16 MFMA — DMA double-buffered (uniform-exec) ----------------
// Per-wave LDS: Zr @0 (48x80B), Zi @3840, bufA @7680 (3072B), bufB @10752; WB2=13824.
// buf: 16 rows x 160B ([pl(2)][c(8)], 40 floats t in [tb-8,tb+32)), W @2560 (32 f),
//      scrap @2688 (384B, dummy tasks 168-191).
// ALL dma16 calls execute with all 64 lanes active (uniform base = lane0 ptr, m104).
// Halo (t<0, chunk 0) handled by clamped per-lane SOURCE + post-wait zero ds_write.
#define WB2 13824

__global__ __launch_bounds__(256, 2) void rp_mfma_kernel(const float* __restrict__ mr,
                                                         const float* __restrict__ mi,
                                                         const float* __restrict__ W,
                                                         float2* __restrict__ Rout,
                                                         float2* __restrict__ Pout) {
    __shared__ __align__(16) unsigned char SH[4 * WB2];
    const int lane = threadIdx.x & 63;
    const int wid = threadIdx.x >> 6;
    const int bf = blockIdx.x * 4 + wid;
    unsigned char* base = SH + wid * WB2;
    unsigned char* b0 = base + 7680;
    unsigned char* b1 = base + 10752;

    const float* mrp = mr + (size_t)bf * C * T;
    const float* mip = mi + (size_t)bf * C * T;
    const float* Wp  = W  + (size_t)bf * T;

    const int q = lane >> 4, col = lane & 15;
    const int pc = lane >> 3, pg = lane & 7;     // phase-B task: channel, 4t-group

    const int PM[6] = {0, 0, 0, 1, 1, 2};
    const int PN[6] = {0, 1, 2, 1, 2, 2};

    // per-lane DMA sources (loop-invariant); task = lane + it*64, 192 tasks total
    const float* sb[3];    // steady-state source (add ntb floats per chunk)
    const float* sb0[3];   // prologue source (halo clamped to t=0)
    bool hal[3];
#pragma unroll
    for (int it = 0; it < 3; ++it) {
        int task = lane + it * 64;
        hal[it] = false;
        if (task < 160) {
            int row = task / 10, grp = task - row * 10;
            int pl = row >> 3, c = row & 7;
            const float* cb = (pl ? mip : mrp) + c * T;
            sb[it] = cb + grp * 4 - 8;
            hal[it] = (grp < 2);
            sb0[it] = hal[it] ? cb : sb[it];
        } else if (task < 168) {
            sb[it] = Wp + (task - 160) * 4;
            sb0[it] = sb[it];
        } else {
            sb[it] = mrp + (task - 168) * 4;   // dummy -> scrap slot
            sb0[it] = sb[it];
        }
    }

    f32x4 accRe[6], accIr[6], accRi[6];
#pragma unroll
    for (int p = 0; p < 6; ++p) {
        accRe[p] = (f32x4){0.f, 0.f, 0.f, 0.f};
        accIr[p] = (f32x4){0.f, 0.f, 0.f, 0.f};
        accRi[p] = (f32x4){0.f, 0.f, 0.f, 0.f};
    }

    // prologue: chunk 0 -> buf0 (all lanes active; halo sources clamped)
#pragma unroll
    for (int it = 0; it < 3; ++it)
        dma16(sb0[it], b0 + (lane + it * 64) * 16);
    asm volatile("s_waitcnt vmcnt(0)" ::: "memory");
    // zero the halo slots (their true values are t<0 -> 0); per-lane ds_write is fine
#pragma unroll
    for (int it = 0; it < 3; ++it) {
        int task = lane + it * 64;
        if (hal[it])
            *(float4*)(b0 + task * 16) = make_float4(0.f, 0.f, 0.f, 0.f);
    }
    __builtin_amdgcn_sched_barrier(0);

    for (int ks = 0; ks < 25; ++ks) {
        unsigned char* buf = (ks & 1) ? b1 : b0;
        unsigned char* nbuf = (ks & 1) ? b0 : b1;
        int ntb = (ks < 24) ? (ks + 1) * 32 : ks * 32;   // last: dummy reload (valid addrs)
        // issue next chunk's DMA (stays in flight across this chunk's compute)
#pragma unroll
        for (int it = 0; it < 3; ++it)
            dma16(sb[it] + ntb, nbuf + (lane + it * 64) * 16);
        // current buf complete when outstanding <= 3 (FIFO)
        asm volatile("s_waitcnt vmcnt(3)" ::: "memory");
        __builtin_amdgcn_sched_barrier(0);

        // ---- Phase B: build 6 shift-variant bf16 rows from buf ----
        {
            const float* yrr = (const float*)(buf + pc * 160);
            const float* yir = (const float*)(buf + (8 + pc) * 160);
            float yre[12], yim[12];
            float4 r0 = *(const float4*)(yrr + pg * 4);
            float4 r1 = *(const float4*)(yrr + pg * 4 + 4);
            float4 r2 = *(const float4*)(yrr + pg * 4 + 8);
            float4 i0 = *(const float4*)(yir + pg * 4);
            float4 i1 = *(const float4*)(yir + pg * 4 + 4);
            float4 i2 = *(const float4*)(yir + pg * 4 + 8);
            yre[0] = r0.x; yre[1] = r0.y; yre[2]  = r0.z; yre[3]  = r0.w;
            yre[4] = r1.x; yre[5] = r1.y; yre[6]  = r1.z; yre[7]  = r1.w;
            yre[8] = r2.x; yre[9] = r2.y; yre[10] = r2.z; yre[11] = r2.w;
            yim[0] = i0.x; yim[1] = i0.y; yim[2]  = i0.z; yim[3]  = i0.w;
            yim[4] = i1.x; yim[5] = i1.y; yim[6]  = i1.z; yim[7]  = i1.w;
            yim[8] = i2.x; yim[9] = i2.y; yim[10] = i2.z; yim[11] = i2.w;
            float4 w4 = *(const float4*)(buf + 2560 + pg * 16);
            float wv[4] = {w4.x, w4.y, w4.z, w4.w};
#pragma unroll
            for (int v = 0; v < 6; ++v) {
                int row = (v < 5) ? (v * 8 + pc) : (40 + pc);
                int off = (v < 5) ? (5 - v) : 8;
                bf16x4 zr, zi;
#pragma unroll
                for (int e = 0; e < 4; ++e) {
                    zr[e] = (__bf16)(wv[e] * yre[off + e]);
                    zi[e] = (__bf16)(wv[e] * yim[off + e]);
                }
                *(bf16x4*)(base + row * 80 + pg * 8) = zr;
                *(bf16x4*)(base + 3840 + row * 80 + pg * 8) = zi;
            }
        }

        // ---- fragments (shared A/B operand) + 24 MFMA ----
        bf16x8 fr[3], fi[3];
#pragma unroll
        for (int X = 0; X < 3; ++X) {
            fr[X] = *(const bf16x8*)(base + (X * 16 + col) * 80 + q * 16);
            fi[X] = *(const bf16x8*)(base + 3840 + (X * 16 + col) * 80 + q * 16);
        }
#pragma unroll
        for (int p = 0; p < 6; ++p) {
            int mt = PM[p], nt = PN[p];
            accRe[p] = __builtin_amdgcn_mfma_f32_16x16x32_bf16(fr[mt], fr[nt], accRe[p], 0, 0, 0);
            accRe[p] = __builtin_amdgcn_mfma_f32_16x16x32_bf16(fi[mt], fi[nt], accRe[p], 0, 0, 0);
            accIr[p] = __builtin_amdgcn_mfma_f32_16x16x32_bf16(fi[mt], fr[nt], accIr[p], 0, 0, 0);
            accRi[p] = __builtin_amdgcn_mfma_f32_16x16x32_bf16(fr[mt], fi[nt], accRi[p], 0, 0, 0);
        }
    }

    // ---- epilogue: D row=(lane>>4)*4+reg, col=lane&15 (m89); Hermitian mirror ----
    // EPS_REG added on the diagonal here.
    float2* Rp = Rout + (size_t)bf * K * K;
    float2* Pp = Pout + (size_t)bf * K * C;
#pragma unroll
    for (int p = 0; p < 6; ++p) {
        int mt = PM[p], nt = PN[p];
#pragma unroll
        for (int r = 0; r < 4; ++r) {
            int m = mt * 16 + q * 4 + r;
            int n = nt * 16 + col;
            float re = accRe[p][r];
            float im = accIr[p][r] - accRi[p][r];
            if (m < K) {
                if (n < K) {
                    if (m == n) re += 1e-10f;
                    Rp[m * K + n] = make_float2(re, im);
                } else {
                    Pp[m * C + (n - K)] = make_float2(re, im);
                }
            }
            if (mt != nt && m < K && n < K)
                Rp[n * K + m] = make_float2(re, -im);
        }
    }
}

// ---------------- kernel 3: solve R G = P — register GJ, high-VGPR launch bounds ----------------
__device__ __forceinline__ float rdlane(float v, int j) {
    return __uint_as_float(__builtin_amdgcn_readlane(__float_as_uint(v), (unsigned)j));
}

__global__ __launch_bounds__(64, 2) void solve_kernel(const float2* __restrict__ Rin,
                                                      const float2* __restrict__ Pin,
                                                      float2* __restrict__ Gout) {
    const int bf = blockIdx.x;
    const int lane = threadIdx.x;
    const bool act = lane < K;

    float2 row[NCOL];
    {
        const float4* Rp4 = (const float4*)(Rin + (size_t)bf * K * K + (size_t)(act ? lane : 0) * K);
        const float4* Pp4 = (const float4*)(Pin + (size_t)bf * K * C + (size_t)(act ? lane : 0) * C);
#pragma unroll
        for (int m = 0; m < K / 2; ++m) {
            float4 v = Rp4[m];
            if (!act) v = make_float4(0.f, 0.f, 0.f, 0.f);
            row[2 * m]     = make_float2(v.x, v.y);
            row[2 * m + 1] = make_float2(v.z, v.w);
        }
#pragma unroll
        for (int m = 0; m < C / 2; ++m) {
            float4 v = Pp4[m];
            if (!act) v = make_float4(0.f, 0.f, 0.f, 0.f);
            row[K + 2 * m]     = make_float2(v.x, v.y);
            row[K + 2 * m + 1] = make_float2(v.z, v.w);
        }
    }

#pragma unroll
    for (int j = 0; j < K; ++j) {
        float dx = rdlane(row[j].x, j);
        float dy = rdlane(row[j].y, j);
        float den = fmaf(dx, dx, dy * dy);
        float r = 1.0f / den;
        float ix = dx * r;
        float iy = -dy * r;
        float lx = row[j].x * ix - row[j].y * iy;
        float ly = row[j].x * iy + row[j].y * ix;
        bool isj = (lane == j);
        lx = isj ? (1.0f - ix) : lx;
        ly = isj ? (0.0f - iy) : ly;
#pragma unroll
        for (int n = j; n < NCOL; ++n) {
            float ux = rdlane(row[n].x, j);
            float uy = rdlane(row[n].y, j);
            row[n].x = fmaf(-lx, ux, fmaf( ly, uy, row[n].x));
            row[n].y = fmaf(-lx, uy, fmaf(-ly, ux, row[n].y));
        }
    }

    if (act) {
        float4* Gp = (float4*)(Gout + (size_t)bf * K * C + (size_t)lane * C);
#pragma unroll
        for (int m = 0; m < C / 2; ++m)
            Gp[m] = make_float4(row[K + 2 * m].x, row[K + 2 * m].y,
                                row[K + 2 * m + 1].x, row[K + 2 * m + 1].y);
    }
}

// ---------------- kernel 4: X via bf16 MFMA — prefetch + epilogue-Y-from-LDS ----------------
#define XSTR 144
#define XWB 12032

__device__ __forceinline__ PF x_load(const float* __restrict__ mrp,
                                     const float* __restrict__ mip,
                                     int tb, int lane) {
    PF p;
#pragma unroll
    for (int it = 0; it < 3; ++it) {
        int task = lane + it * 64;
        float4 v = make_float4(0.f, 0.f, 0.f, 0.f);
        if (task < 160) {
            int pl = task / 80;
            int rem = task - pl * 80;
            int c = rem / 10, grp = rem - c * 10;
            int tg = tb - 8 + grp * 4;
            const float* srcp = pl ? mip : mrp;
            if (tg >= 0) v = *(const float4*)(srcp + c * T + tg);
        }
        p.v[it] = v;
    }
    return p;
}

__device__ __forceinline__ void x_store(const PF& p, float* sre, float* sim_, int lane) {
#pragma unroll
    for (int it = 0; it < 3; ++it) {
        int task = lane + it * 64;
        if (task < 160) {
            int pl = task / 80;
            int rem = task - pl * 80;
            int c = rem / 10, grp = rem - c * 10;
            *(float4*)((pl ? sim_ : sre) + c * 44 + grp * 4) = p.v[it];
        }
    }
}

__global__ __launch_bounds__(64) void x_mfma_kernel(const float* __restrict__ mr,
                                                    const float* __restrict__ mi,
                                                    const float2* __restrict__ Gin,
                                                    const int* __restrict__ ilens,
                                                    float2* __restrict__ out) {
    __shared__ __align__(16) unsigned char SH[XWB];
    const int lane = threadIdx.x;
    const int gid = blockIdx.x;
    const int bf = gid >> 2;
    const int split = gid & 3;
    const int ck0 = (split == 0) ? 0 : (1 + split * 6);
    const int nck = (split == 0) ? 7 : 6;
    unsigned char* base = SH;
    float* sre = (float*)(base + 9216);
    float* sim_ = (float*)(base + 10624);

    const float* mrp = mr + (size_t)bf * C * T;
    const float* mip = mi + (size_t)bf * C * T;
    const float2* Gp = Gin + (size_t)bf * K * C;
    float2* outp = out + (size_t)bf * C * T;
    const int len = ilens[bf / F];

    const int q = lane >> 4, col = lane & 15;
    const int t2 = lane >> 1, half = lane & 1;

    // ---- one-time: zero-fill bytes [80,128) of all rows (a = 40..63 -> 0.0) ----
#pragma unroll
    for (int pl = 0; pl < 2; ++pl) {
        unsigned char* pb = base + pl * 4608 + t2 * XSTR + 80 + half * 24;
        *(float2*)(pb)      = make_float2(0.f, 0.f);
        *(float2*)(pb + 8)  = make_float2(0.f, 0.f);
        *(float2*)(pb + 16) = make_float2(0.f, 0.f);
    }

    // ---- A fragments: G (and -Gi) in registers, built once ----
    bf16x8 Agr[2], Agi[2], Agin[2];
#pragma unroll
    for (int ks = 0; ks < 2; ++ks)
#pragma unroll
        for (int j = 0; j < 8; ++j) {
            int a = ks * 32 + q * 8 + j;
            float2 g = make_float2(0.f, 0.f);
            if (a < K && col < C) g = Gp[a * C + col];
            Agr[ks][j]  = (__bf16)g.x;
            Agi[ks][j]  = (__bf16)g.y;
            Agin[ks][j] = (__bf16)(-g.y);
        }

    PF cur = x_load(mrp, mip, ck0 * 32, lane);

    for (int ci = 0; ci < nck; ++ci) {
        const int tb = (ck0 + ci) * 32;

        // ---- write staged chunk; prefetch next ----
        x_store(cur, sre, sim_, lane);
        if (ci + 1 < nck) cur = x_load(mrp, mip, tb + 32, lane);

        // ---- Phase B: build transposed bf16 Ytilde rows [t_local][a] ----
#pragma unroll
        for (int i = 0; i < 5; ++i) {
            int abase = half * 20 + 4 * i;
            bf16x4 zr, zi;
#pragma unroll
            for (int e2 = 0; e2 < 4; ++e2) {
                int a = abase + e2;
                int v = a >> 3, c = a & 7;
                int idx = c * 44 + t2 + 5 - v;   // Y[c][tb+t2-3-v]
                zr[e2] = (__bf16)sre[idx];
                zi[e2] = (__bf16)sim_[idx];
            }
            *(bf16x4*)(base + t2 * XSTR + abase * 2) = zr;
            *(bf16x4*)(base + 4608 + t2 * XSTR + abase * 2) = zi;
        }

        // ---- two 16-t tiles: 8 MFMA each + epilogue (Y from scratch LDS) ----
#pragma unroll
        for (int tt = 0; tt < 2; ++tt) {
            const int trow = tt * 16 + col;
            f32x4 accRe = (f32x4){0.f, 0.f, 0.f, 0.f};
            f32x4 accIm = (f32x4){0.f, 0.f, 0.f, 0.f};
#pragma unroll
            for (int ks = 0; ks < 2; ++ks) {
                bf16x8 byr = *(const bf16x8*)(base + trow * XSTR + ks * 64 + q * 16);
                bf16x8 byi = *(const bf16x8*)(base + 4608 + trow * XSTR + ks * 64 + q * 16);
                accRe = __builtin_amdgcn_mfma_f32_16x16x32_bf16(Agr[ks], byr, accRe, 0, 0, 0);
                accRe = __builtin_amdgcn_mfma_f32_16x16x32_bf16(Agi[ks], byi, accRe, 0, 0, 0);
                accIm = __builtin_amdgcn_mfma_f32_16x16x32_bf16(Agr[ks], byi, accIm, 0, 0, 0);
                accIm = __builtin_amdgcn_mfma_f32_16x16x32_bf16(Agin[ks], byr, accIm, 0, 0, 0);
            }
            // D row=(lane>>4)*4+r (=e), col=lane&15 (=t offset) [m89]
            if (q < 2) {
                int t = tb + tt * 16 + col;
                int l = tt * 16 + col + 8;       // scratch index of t
                bool ok = (t < len);
#pragma unroll
                for (int r = 0; r < 4; ++r) {
                    int e = q * 4 + r;
                    float yr = sre[e * 44 + l];
                    float yi = sim_[e * 44 + l];
                    float2 v = ok ? make_float2(yr - accRe[r], yi - accIm[r])
                                  : make_float2(0.f, 0.f);
                    outp[e * T + t] = v;
                }
            }
        }
    }
}

extern "C" void kernel_launch(void* const* d_in, const int* in_sizes, int n_in,
                              void* d_out, int out_size, void* d_ws, size_t ws_size,
                              hipStream_t stream) {
    const float* sep_r = (const float*)d_in[0];
    const float* sep_i = (const float*)d_in[1];
    const float* mix_r = (const float*)d_in[2];
    const float* mix_i = (const float*)d_in[3];
    const int* ilens   = (const int*)d_in[4];

    float* ws = (float*)d_ws;
    float* W = ws;                                        // BF*T floats
    float2* Rws = (float2*)(ws + (size_t)BF * T);         // BF*K*K float2
    float2* Gws = Rws + (size_t)BF * K * K;               // BF*K*C float2 (P then G in-place)

    power_kernel<<<BF, 256, 0, stream>>>(sep_r, sep_i, W);
    rp_mfma_kernel<<<BF / 4, 256, 0, stream>>>(mix_r, mix_i, W, Rws, Gws);
    solve_kernel<<<BF, 64, 0, stream>>>(Rws, Gws, Gws);
    x_mfma_kernel<<<BF * 4, 64, 0, stream>>>(mix_r, mix_i, Gws, ilens, (float2*)d_out);
}